// Round 2
// baseline (226.257 us; speedup 1.0000x reference)
//
#include <hip/hip_runtime.h>
#include <math.h>

#define NPROB (64 * 2048)

__host__ __device__ constexpr int TRI(int i, int j) { return i * 13 - i * (i - 1) / 2 + (j - i); }
__host__ __device__ constexpr int OI6(int i, int j) { return i * 6 - i * (i - 1) / 2 + (j - i); }
__host__ __device__ constexpr int QI(int i, int j)  { return i * 7 - i * (i - 1) / 2 + (j - i); }

// Sparse pattern of P's columns. Entry value = s * T[a][b], or s*1.0 if a==3.
struct PE { int r, a, b, s; };
__device__ constexpr int PLEN[7] = {6, 6, 6, 3, 3, 3, 13};
__device__ constexpr PE PAT[7][13] = {
    {{1,0,2,1},{2,0,1,-1},{4,1,2,1},{5,1,1,-1},{7,2,2,1},{8,2,1,-1}},
    {{0,0,2,-1},{2,0,0,1},{3,1,2,-1},{5,1,0,1},{6,2,2,-1},{8,2,0,1}},
    {{0,0,1,1},{1,0,0,-1},{3,1,1,1},{4,1,0,-1},{6,2,1,1},{7,2,0,-1}},
    {{10,0,0,1},{11,1,0,1},{12,2,0,1}},
    {{10,0,1,1},{11,1,1,1},{12,2,1,1}},
    {{10,0,2,1},{11,1,2,1},{12,2,2,1}},
    {{0,0,0,1},{1,0,1,1},{2,0,2,1},{3,1,0,1},{4,1,1,1},{5,1,2,1},
     {6,2,0,1},{7,2,1,1},{8,2,2,1},{9,3,0,1},{10,0,3,1},{11,1,3,1},{12,2,3,1}},
};

// Build Q-column L: y = M * p_L in fp32, then acc_k = p_k^T y in fp64 for k<=L.
// Identical FMA sequences to the round-1 kernel -> bitwise identical Q entries.
template <int L, typename F>
__device__ __forceinline__ void build_col(const float mreg[91], const float tf[3][4],
                                          const double t[3][4], F emit) {
    float y[13];
    #pragma unroll
    for (int r = 0; r < 13; ++r) y[r] = 0.0f;
    #pragma unroll
    for (int e = 0; e < 13; ++e) {
        if (e < PLEN[L]) {
            const PE pe = PAT[L][e];
            const float tt = (pe.a == 3) ? 1.0f : tf[pe.a][pe.b];
            const float cf = (pe.s > 0) ? tt : -tt;
            const int c = pe.r;
            #pragma unroll
            for (int r = 0; r < 13; ++r)
                y[r] += cf * mreg[(r <= c) ? TRI(r, c) : TRI(c, r)];
        }
    }
    #pragma unroll
    for (int k = 0; k <= L; ++k) {
        double acc = 0.0;
        #pragma unroll
        for (int e = 0; e < 13; ++e) {
            if (e < PLEN[k]) {
                const PE pe = PAT[k][e];
                const double tt = (pe.a == 3) ? 1.0 : t[pe.a][pe.b];
                const double coef = (pe.s > 0) ? tt : -tt;
                acc += coef * (double)y[pe.r];
            }
        }
        emit(k, acc);
    }
}

// Wave-pair decomposition: waves (0,1) own problems [0,64) of the block,
// waves (2,3) own [64,128). Even wave = solver (A): builds cols {1,3,6},
// assembles full Q, runs solve/expm/update, writes outputs. Odd wave =
// builder (B): builds cols {0,2,4,5}, ships 15 Q-entries via LDS, receives
// updated T via LDS. 1024 blocks * 4 waves = 4096 waves = 4 waves/SIMD.
__global__ __launch_bounds__(256) void gn5_kernel(const float* __restrict__ Mg,
                                                  const float* __restrict__ Tg,
                                                  float* __restrict__ outg) {
    const int tid  = threadIdx.x;
    const int lane = tid & 63;
    const int wv   = tid >> 6;
    const int pair = wv >> 1;
    const int role = wv & 1;  // 0 = solver A, 1 = builder B
    const long long prob = (long long)blockIdx.x * 128 + (long long)pair * 64 + lane;

    // LDS (28672 B): per pair-region (14336 B = 1792 doubles):
    //   qx   [64][15] doubles @ +0     (B -> A, Q entries of cols {0,2,4,5})
    //   tb   [64][13] doubles @ +960d  (A -> B, updated T rows; stride 13 pads banks)
    //   stash[64][21] doubles @ +0     (A only, it==4 Omega; overlays qx+tb after
    //                                   their last reads, program-order safe)
    // Prologue staging buf (32*169 fp32 = 21632 B) overlays everything; a
    // __syncthreads separates the phases.
    __shared__ __align__(16) char smem[28672];
    float* buf = (float*)smem;
    double* smemd = (double*)smem;
    double* qx    = smemd + pair * 1792 + lane * 15;
    double* tb    = smemd + pair * 1792 + 960 + lane * 13;
    double* stash = smemd + pair * 1792 + lane * 21;

    float mreg[91];

    // ---- prologue: stage 32 problems at a time, both waves of a pair pull
    // the same triangles (91 fp32) into registers ----
    #pragma unroll 1
    for (int c = 0; c < 4; ++c) {
        const long long p0 = (long long)blockIdx.x * 128 + c * 32;
        const float4* src = (const float4*)(Mg + p0 * 169);
        float4* dst = (float4*)buf;
        #pragma unroll 1
        for (int i = tid; i < (32 * 169) / 4; i += 256) dst[i] = src[i];
        __syncthreads();
        if (pair == (c >> 1) && (lane >> 5) == (c & 1)) {
            const int lidx = lane & 31;
            #pragma unroll
            for (int i = 0; i < 13; ++i)
                #pragma unroll
                for (int j = i; j < 13; ++j)
                    mreg[TRI(i, j)] = buf[lidx * 169 + i * 13 + j];
        }
        __syncthreads();
    }

    // Load T rows 0..2 (bottom row stays (0,0,0,1)).
    double t[3][4];
    {
        const float* tp = Tg + prob * 16;
        #pragma unroll
        for (int i = 0; i < 3; ++i)
            #pragma unroll
            for (int j = 0; j < 4; ++j)
                t[i][j] = (double)tp[i * 4 + j];
    }

    double q[28];  // solver's symmetric 7x7 upper triangle

    #pragma unroll 1
    for (int it = 0; it < 5; ++it) {
        float tf[3][4];
        #pragma unroll
        for (int i = 0; i < 3; ++i)
            #pragma unroll
            for (int j = 0; j < 4; ++j)
                tf[i][j] = (float)t[i][j];

        if (role == 1) {
            // builder: cols {0,2,4,5} -> qx slots {0, 1..3, 4..8, 9..14}
            build_col<0>(mreg, tf, t, [&](int k, double a) { qx[0 + k] = a; });
            build_col<2>(mreg, tf, t, [&](int k, double a) { qx[1 + k] = a; });
            build_col<4>(mreg, tf, t, [&](int k, double a) { qx[4 + k] = a; });
            build_col<5>(mreg, tf, t, [&](int k, double a) { qx[9 + k] = a; });
        } else {
            // solver: cols {1,3,6}
            build_col<1>(mreg, tf, t, [&](int k, double a) { q[QI(k, 1)] = a; });
            build_col<3>(mreg, tf, t, [&](int k, double a) { q[QI(k, 3)] = a; });
            build_col<6>(mreg, tf, t, [&](int k, double a) { q[QI(k, 6)] = a; });
        }

        __syncthreads();  // bar1: qx visible to solver

        if (role == 0) {
            // assemble partner's entries
            q[QI(0, 0)] = qx[0];
            #pragma unroll
            for (int k = 0; k <= 2; ++k) q[QI(k, 2)] = qx[1 + k];
            #pragma unroll
            for (int k = 0; k <= 4; ++k) q[QI(k, 4)] = qx[4 + k];
            #pragma unroll
            for (int k = 0; k <= 5; ++k) q[QI(k, 5)] = qx[9 + k];

            // ---- regularization ----
            const double trQ  = q[QI(3, 3)] + q[QI(4, 4)] + q[QI(5, 5)];
            const double regT = 1e-8 * fmax(trQ, 1.0);
            q[QI(0, 0)] += 10.0;
            q[QI(1, 1)] += 10.0;
            q[QI(2, 2)] += 10.0;
            q[QI(3, 3)] += regT;
            q[QI(4, 4)] += regT;
            q[QI(5, 5)] += regT;

            // ---- reg2 = 1e-5 * (1 + max(Omega)), fmax tree ----
            const double a0 = fmax(q[QI(0,0)], q[QI(0,1)]);
            const double a1 = fmax(q[QI(0,2)], q[QI(0,3)]);
            const double a2 = fmax(q[QI(0,4)], q[QI(0,5)]);
            const double a3 = fmax(q[QI(1,1)], q[QI(1,2)]);
            const double a4 = fmax(q[QI(1,3)], q[QI(1,4)]);
            const double a5 = fmax(q[QI(1,5)], q[QI(2,2)]);
            const double a6 = fmax(q[QI(2,3)], q[QI(2,4)]);
            const double a7 = fmax(q[QI(2,5)], q[QI(3,3)]);
            const double a8 = fmax(q[QI(3,4)], q[QI(3,5)]);
            const double a9 = fmax(q[QI(4,4)], q[QI(4,5)]);
            const double b0 = fmax(a0, a1);
            const double b1 = fmax(a2, a3);
            const double b2 = fmax(a4, a5);
            const double b3 = fmax(a6, a7);
            const double b4 = fmax(fmax(a8, a9), q[QI(5,5)]);
            const double mx = fmax(fmax(b0, b1), fmax(fmax(b2, b3), b4));
            const double reg2 = 1e-5 * (1.0 + mx);

            // last iteration: stash Omega (post-diag, pre-reg2) before GE
            // destroys q. stash overlays qx (already consumed above) + tb
            // (dead after it==3's read) — program order within this wave
            // makes the qx-read -> stash-write ordering safe.
            if (it == 4) {
                #pragma unroll
                for (int k = 0; k < 6; ++k)
                    #pragma unroll
                    for (int l = k; l < 6; ++l)
                        stash[OI6(k, l)] = q[QI(k, l)];
            }

            #pragma unroll
            for (int k = 0; k < 6; ++k) q[QI(k, k)] += reg2;

            // ---- in-place symmetric GE on q, col 6 as RHS ----
            #pragma unroll
            for (int k = 0; k < 6; ++k) {
                const double inv = 1.0 / q[QI(k, k)];
                q[QI(k, k)] = inv;
                #pragma unroll
                for (int i = k + 1; i < 6; ++i) {
                    const double f = q[QI(k, i)] * inv;
                    #pragma unroll
                    for (int j = i; j < 7; ++j) q[QI(i, j)] -= f * q[QI(k, j)];
                }
            }
            double x[6];
            #pragma unroll
            for (int i = 5; i >= 0; --i) {
                double s = q[QI(i, 6)];
                #pragma unroll
                for (int j = i + 1; j < 6; ++j) s -= q[QI(i, j)] * x[j];
                x[i] = s * q[QI(i, i)];
            }
            const double wx = -x[0], wy = -x[1], wz = -x[2];
            const double ux = -x[3], uy = -x[4], uz = -x[5];

            // ---- closed-form expm of se(3) ----
            const double tsq = wx * wx + wy * wy + wz * wz;
            double A, B, Cc;
            if (tsq < 0.25) {
                A  = 1.0 + tsq * (-1.0/6 + tsq * (1.0/120 + tsq * (-1.0/5040 + tsq * (1.0/362880
                     + tsq * (-1.0/39916800.0 + tsq * (1.0/6227020800.0 + tsq * (-1.0/1307674368000.0)))))));
                B  = 0.5 + tsq * (-1.0/24 + tsq * (1.0/720 + tsq * (-1.0/40320 + tsq * (1.0/3628800
                     + tsq * (-1.0/479001600.0 + tsq * (1.0/87178291200.0 + tsq * (-1.0/20922789888000.0)))))));
                Cc = 1.0/6 + tsq * (-1.0/120 + tsq * (1.0/5040 + tsq * (-1.0/362880 + tsq * (1.0/39916800.0
                     + tsq * (-1.0/6227020800.0 + tsq * (1.0/1307674368000.0 + tsq * (-1.0/355687428096000.0)))))));
            } else {
                const double th = sqrt(tsq);
                const double s = sin(th), c = cos(th);
                A  = s / th;
                B  = (1.0 - c) / tsq;
                Cc = (th - s) / (tsq * th);
            }
            const double K2xx = wx * wx - tsq, K2yy = wy * wy - tsq, K2zz = wz * wz - tsq;
            const double K2xy = wx * wy, K2xz = wx * wz, K2yz = wy * wz;
            double R[3][3];
            R[0][0] = 1.0 + B * K2xx;      R[0][1] = -A * wz + B * K2xy;  R[0][2] =  A * wy + B * K2xz;
            R[1][0] =  A * wz + B * K2xy;  R[1][1] = 1.0 + B * K2yy;      R[1][2] = -A * wx + B * K2yz;
            R[2][0] = -A * wy + B * K2xz;  R[2][1] =  A * wx + B * K2yz;  R[2][2] = 1.0 + B * K2zz;
            const double V00 = 1.0 + Cc * K2xx,      V01 = -B * wz + Cc * K2xy, V02 =  B * wy + Cc * K2xz;
            const double V10 =  B * wz + Cc * K2xy,  V11 = 1.0 + Cc * K2yy,     V12 = -B * wx + Cc * K2yz;
            const double V20 = -B * wy + Cc * K2xz,  V21 =  B * wx + Cc * K2yz, V22 = 1.0 + Cc * K2zz;
            const double ex = V00 * ux + V01 * uy + V02 * uz;
            const double ey = V10 * ux + V11 * uy + V12 * uz;
            const double ez = V20 * ux + V21 * uy + V22 * uz;

            // ---- T = T @ E ----
            #pragma unroll
            for (int i = 0; i < 3; ++i) {
                const double c0_ = t[i][0], c1_ = t[i][1], c2_ = t[i][2], c3_ = t[i][3];
                t[i][0] = c0_ * R[0][0] + c1_ * R[1][0] + c2_ * R[2][0];
                t[i][1] = c0_ * R[0][1] + c1_ * R[1][1] + c2_ * R[2][1];
                t[i][2] = c0_ * R[0][2] + c1_ * R[1][2] + c2_ * R[2][2];
                t[i][3] = c0_ * ex + c1_ * ey + c2_ * ez + c3_;
            }

            if (it < 4) {
                #pragma unroll
                for (int i = 0; i < 3; ++i)
                    #pragma unroll
                    for (int j = 0; j < 4; ++j)
                        tb[i * 4 + j] = t[i][j];
            }
        }

        if (it < 4) {
            __syncthreads();  // bar2: tb visible to builder
            if (role == 1) {
                #pragma unroll
                for (int i = 0; i < 3; ++i)
                    #pragma unroll
                    for (int j = 0; j < 4; ++j)
                        t[i][j] = tb[i * 4 + j];
            }
        }
    }

    // ---- outputs (solver wave only) ----
    if (role == 0) {
        float* to = outg + prob * 16;
        #pragma unroll
        for (int i = 0; i < 3; ++i)
            #pragma unroll
            for (int j = 0; j < 4; ++j)
                to[i * 4 + j] = (float)t[i][j];
        to[12] = 0.0f; to[13] = 0.0f; to[14] = 0.0f; to[15] = 1.0f;

        const double invden = 1.0 / (t[2][3] * t[2][3] + 1e-8);
        float* oo = outg + (long long)NPROB * 16 + prob * 36;
        #pragma unroll
        for (int k = 0; k < 6; ++k)
            #pragma unroll
            for (int l = 0; l < 6; ++l)
                oo[k * 6 + l] = (float)(stash[(k <= l) ? OI6(k, l) : OI6(l, k)] * invden);
    }
}

extern "C" void kernel_launch(void* const* d_in, const int* in_sizes, int n_in,
                              void* d_out, int out_size, void* d_ws, size_t ws_size,
                              hipStream_t stream) {
    const float* Mg = (const float*)d_in[0];  // [64,2048,13,13] fp32
    const float* Tg = (const float*)d_in[1];  // [64,2048,4,4]  fp32
    float* out = (float*)d_out;               // [NPROB*16 + NPROB*36] fp32
    (void)in_sizes; (void)n_in; (void)out_size; (void)d_ws; (void)ws_size;

    const int threads = 256;
    const int blocks = NPROB / 128;  // 1024 blocks, 2 waves per 64 problems
    gn5_kernel<<<blocks, threads, 0, stream>>>(Mg, Tg, out);
}

// Round 3
// 165.182 us; speedup vs baseline: 1.3697x; 1.3697x over previous
//
#include <hip/hip_runtime.h>
#include <math.h>

#define NPROB (64 * 2048)

__host__ __device__ constexpr int TRI(int i, int j) { return i * 13 - i * (i - 1) / 2 + (j - i); }
__host__ __device__ constexpr int OI6(int i, int j) { return i * 6 - i * (i - 1) / 2 + (j - i); }
__host__ __device__ constexpr int QI(int i, int j)  { return i * 7 - i * (i - 1) / 2 + (j - i); }

// Sparse pattern of P's columns. Entry value = s * T[a][b], or s*1.0 if a==3.
// P rows (13): rot_rows(i) -> rows 3i..3i+2, ones row 9, translation rows 10..12.
struct PE { int r, a, b, s; };
__device__ constexpr int PLEN[7] = {6, 6, 6, 3, 3, 3, 13};
__device__ constexpr PE PAT[7][13] = {
    // col0: row 3i+1 = +c_i (t[i][2]), row 3i+2 = -b_i (t[i][1])
    {{1,0,2,1},{2,0,1,-1},{4,1,2,1},{5,1,1,-1},{7,2,2,1},{8,2,1,-1}},
    // col1: row 3i+0 = -c_i, row 3i+2 = +a_i (t[i][0])
    {{0,0,2,-1},{2,0,0,1},{3,1,2,-1},{5,1,0,1},{6,2,2,-1},{8,2,0,1}},
    // col2: row 3i+0 = +b_i, row 3i+1 = -a_i
    {{0,0,1,1},{1,0,0,-1},{3,1,1,1},{4,1,0,-1},{6,2,1,1},{7,2,0,-1}},
    // col3: row 10+i = a_i
    {{10,0,0,1},{11,1,0,1},{12,2,0,1}},
    // col4: row 10+i = b_i
    {{10,0,1,1},{11,1,1,1},{12,2,1,1}},
    // col5: row 10+i = c_i
    {{10,0,2,1},{11,1,2,1},{12,2,2,1}},
    // col6: row 3i+j = t[i][j], row 9 = 1, row 10+i = d_i (t[i][3])
    {{0,0,0,1},{1,0,1,1},{2,0,2,1},{3,1,0,1},{4,1,1,1},{5,1,2,1},
     {6,2,0,1},{7,2,1,1},{8,2,2,1},{9,3,0,1},{10,0,3,1},{11,1,3,1},{12,2,3,1}},
};

// Fast fp64 reciprocal: v_rcp_f64 seed + 2 Newton steps -> ~1 ulp.
// Pivots are SPD-diagonal + reg, so w > 0 always (no inf/denorm edge).
// Serial latency ~1/3 of the correctly-rounded fp64 divide sequence.
__device__ __forceinline__ double fast_rcp(double w) {
    double r = __builtin_amdgcn_rcp(w);
    double e = fma(-w, r, 1.0);
    r = fma(r, e, r);
    e = fma(-w, r, 1.0);
    r = fma(r, e, r);
    return r;
}

__global__ __launch_bounds__(256) void gn5_kernel(const float* __restrict__ Mg,
                                                  const float* __restrict__ Tg,
                                                  float* __restrict__ outg) {
    const int tid  = threadIdx.x;
    const int lane = tid & 63;
    const int wv   = tid >> 6;
    const long long prob = (long long)blockIdx.x * 256 + tid;

    // Stage 64 problems (64*169 floats = 43.3 KB) at a time; each wave then
    // pulls its own symmetric triangle (91 fp32) into registers.
    __shared__ __align__(16) float buf[64 * 169];
    float mreg[91];

    #pragma unroll 1
    for (int w = 0; w < 4; ++w) {
        const long long c0 = (long long)blockIdx.x * 256 + (long long)w * 64;
        const float4* src = (const float4*)(Mg + c0 * 169);
        float4* dst = (float4*)buf;
        #pragma unroll 1
        for (int i = tid; i < (64 * 169) / 4; i += 256) dst[i] = src[i];
        __syncthreads();
        if (wv == w) {
            #pragma unroll
            for (int i = 0; i < 13; ++i)
                #pragma unroll
                for (int j = i; j < 13; ++j)
                    mreg[TRI(i, j)] = buf[lane * 169 + i * 13 + j];
        }
        __syncthreads();
    }

    // Load T rows 0..2 (bottom row of input is (0,0,0,1) and stays so).
    double t[3][4];
    {
        const float* tp = Tg + prob * 16;
        #pragma unroll
        for (int i = 0; i < 3; ++i)
            #pragma unroll
            for (int j = 0; j < 4; ++j)
                t[i][j] = (double)tp[i * 4 + j];
    }

    double q[28];  // symmetric 7x7 upper triangle (fp64, post-conversion)

    #pragma unroll 1
    for (int it = 0; it < 5; ++it) {
        // fp32 copy of the pose: both stages of the Q build run in fp32.
        float tf[3][4];
        #pragma unroll
        for (int i = 0; i < 3; ++i)
            #pragma unroll
            for (int j = 0; j < 4; ++j)
                tf[i][j] = (float)t[i][j];

        // ---- Q = P^T M P via sparse columns, all-fp32 build ----
        // M is fp32 data; coefficients are O(1) pose entries. Accumulating
        // stage-2 in fp32 halves its issue cost and removes all f32->f64
        // converts from the build. One 28-entry convert follows.
        float qf[28];
        #pragma unroll
        for (int l = 0; l < 7; ++l) {
            float y[13];
            #pragma unroll
            for (int r = 0; r < 13; ++r) y[r] = 0.0f;
            #pragma unroll
            for (int e = 0; e < 13; ++e) {
                if (e < PLEN[l]) {
                    const PE pe = PAT[l][e];
                    const float tt = (pe.a == 3) ? 1.0f : tf[pe.a][pe.b];
                    const float cf = (pe.s > 0) ? tt : -tt;
                    const int c = pe.r;
                    #pragma unroll
                    for (int r = 0; r < 13; ++r)
                        y[r] += cf * mreg[(r <= c) ? TRI(r, c) : TRI(c, r)];
                }
            }
            #pragma unroll
            for (int k = 0; k <= l; ++k) {
                float acc = 0.0f;
                #pragma unroll
                for (int e = 0; e < 13; ++e) {
                    if (e < PLEN[k]) {
                        const PE pe = PAT[k][e];
                        const float tt = (pe.a == 3) ? 1.0f : tf[pe.a][pe.b];
                        const float cf = (pe.s > 0) ? tt : -tt;
                        acc += cf * y[pe.r];
                    }
                }
                qf[QI(k, l)] = acc;
            }
        }
        #pragma unroll
        for (int i = 0; i < 28; ++i) q[i] = (double)qf[i];

        // ---- regularization: Omega = Q[0:6,0:6] + diag(10,10,10,regT,regT,regT) ----
        const double trQ  = q[QI(3, 3)] + q[QI(4, 4)] + q[QI(5, 5)];
        const double regT = 1e-8 * fmax(trQ, 1.0);
        q[QI(0, 0)] += 10.0;
        q[QI(1, 1)] += 10.0;
        q[QI(2, 2)] += 10.0;
        q[QI(3, 3)] += regT;
        q[QI(4, 4)] += regT;
        q[QI(5, 5)] += regT;

        // ---- _inv's extra reg: 1e-5 * (1 + max(Omega)) (signed max, full 6x6) ----
        // fmax tree (order-independent, shortens the dependent chain).
        const double a0 = fmax(q[QI(0,0)], q[QI(0,1)]);
        const double a1 = fmax(q[QI(0,2)], q[QI(0,3)]);
        const double a2 = fmax(q[QI(0,4)], q[QI(0,5)]);
        const double a3 = fmax(q[QI(1,1)], q[QI(1,2)]);
        const double a4 = fmax(q[QI(1,3)], q[QI(1,4)]);
        const double a5 = fmax(q[QI(1,5)], q[QI(2,2)]);
        const double a6 = fmax(q[QI(2,3)], q[QI(2,4)]);
        const double a7 = fmax(q[QI(2,5)], q[QI(3,3)]);
        const double a8 = fmax(q[QI(3,4)], q[QI(3,5)]);
        const double a9 = fmax(q[QI(4,4)], q[QI(4,5)]);
        const double b0 = fmax(a0, a1);
        const double b1 = fmax(a2, a3);
        const double b2 = fmax(a4, a5);
        const double b3 = fmax(a6, a7);
        const double b4 = fmax(fmax(a8, a9), q[QI(5,5)]);
        const double mx = fmax(fmax(b0, b1), fmax(fmax(b2, b3), b4));
        const double reg2 = 1e-5 * (1.0 + mx);

        // On the last iteration, stash Omega (pre-reg2) in the idle staging
        // buffer before the in-place GE destroys q. Thread-private slots
        // (256 threads * 21 doubles = 43008 B <= 43264 B), no barrier needed.
        if (it == 4) {
            double* st = (double*)buf;
            #pragma unroll
            for (int k = 0; k < 6; ++k)
                #pragma unroll
                for (int l = k; l < 6; ++l)
                    st[(long long)tid * 21 + OI6(k, l)] = q[QI(k, l)];
        }

        #pragma unroll
        for (int k = 0; k < 6; ++k) q[QI(k, k)] += reg2;

        // ---- solve (Omega + reg2*I) x = g, v = -x: in-place symmetric GE on q,
        // col 6 carried as the RHS; pivot reciprocals overwrite the diagonal.
        #pragma unroll
        for (int k = 0; k < 6; ++k) {
            const double inv = fast_rcp(q[QI(k, k)]);
            q[QI(k, k)] = inv;
            #pragma unroll
            for (int i = k + 1; i < 6; ++i) {
                const double f = q[QI(k, i)] * inv;
                #pragma unroll
                for (int j = i; j < 7; ++j) q[QI(i, j)] -= f * q[QI(k, j)];
            }
        }
        double x[6];
        #pragma unroll
        for (int i = 5; i >= 0; --i) {
            double s = q[QI(i, 6)];
            #pragma unroll
            for (int j = i + 1; j < 6; ++j) s -= q[QI(i, j)] * x[j];
            x[i] = s * q[QI(i, i)];
        }
        const double wx = -x[0], wy = -x[1], wz = -x[2];
        const double ux = -x[3], uy = -x[4], uz = -x[5];

        // ---- closed-form expm of se(3): E = [[R, V*u],[0,1]] ----
        const double tsq = wx * wx + wy * wy + wz * wz;
        double A, B, Cc;
        if (tsq < 0.25) {
            // Taylor in t = theta^2, fp64-exact for t < 0.25
            A  = 1.0 + tsq * (-1.0/6 + tsq * (1.0/120 + tsq * (-1.0/5040 + tsq * (1.0/362880
                 + tsq * (-1.0/39916800.0 + tsq * (1.0/6227020800.0 + tsq * (-1.0/1307674368000.0)))))));
            B  = 0.5 + tsq * (-1.0/24 + tsq * (1.0/720 + tsq * (-1.0/40320 + tsq * (1.0/3628800
                 + tsq * (-1.0/479001600.0 + tsq * (1.0/87178291200.0 + tsq * (-1.0/20922789888000.0)))))));
            Cc = 1.0/6 + tsq * (-1.0/120 + tsq * (1.0/5040 + tsq * (-1.0/362880 + tsq * (1.0/39916800.0
                 + tsq * (-1.0/6227020800.0 + tsq * (1.0/1307674368000.0 + tsq * (-1.0/355687428096000.0)))))));
        } else {
            const double th = sqrt(tsq);
            const double s = sin(th), c = cos(th);
            A  = s / th;
            B  = (1.0 - c) / tsq;
            Cc = (th - s) / (tsq * th);
        }
        // K^2 = w w^T - tsq*I
        const double K2xx = wx * wx - tsq, K2yy = wy * wy - tsq, K2zz = wz * wz - tsq;
        const double K2xy = wx * wy, K2xz = wx * wz, K2yz = wy * wz;
        double R[3][3];
        R[0][0] = 1.0 + B * K2xx;      R[0][1] = -A * wz + B * K2xy;  R[0][2] =  A * wy + B * K2xz;
        R[1][0] =  A * wz + B * K2xy;  R[1][1] = 1.0 + B * K2yy;      R[1][2] = -A * wx + B * K2yz;
        R[2][0] = -A * wy + B * K2xz;  R[2][1] =  A * wx + B * K2yz;  R[2][2] = 1.0 + B * K2zz;
        const double V00 = 1.0 + Cc * K2xx,      V01 = -B * wz + Cc * K2xy, V02 =  B * wy + Cc * K2xz;
        const double V10 =  B * wz + Cc * K2xy,  V11 = 1.0 + Cc * K2yy,     V12 = -B * wx + Cc * K2yz;
        const double V20 = -B * wy + Cc * K2xz,  V21 =  B * wx + Cc * K2yz, V22 = 1.0 + Cc * K2zz;
        const double ex = V00 * ux + V01 * uy + V02 * uz;
        const double ey = V10 * ux + V11 * uy + V12 * uz;
        const double ez = V20 * ux + V21 * uy + V22 * uz;

        // ---- T = T @ E ----
        #pragma unroll
        for (int i = 0; i < 3; ++i) {
            const double a0_ = t[i][0], a1_ = t[i][1], a2_ = t[i][2], a3_ = t[i][3];
            t[i][0] = a0_ * R[0][0] + a1_ * R[1][0] + a2_ * R[2][0];
            t[i][1] = a0_ * R[0][1] + a1_ * R[1][1] + a2_ * R[2][1];
            t[i][2] = a0_ * R[0][2] + a1_ * R[1][2] + a2_ * R[2][2];
            t[i][3] = a0_ * ex + a1_ * ey + a2_ * ez + a3_;
        }
    }

    // ---- outputs: T [NPROB,4,4] then Omega/(tz^2+1e-8) [NPROB,6,6], fp32 ----
    {
        float* to = outg + prob * 16;
        #pragma unroll
        for (int i = 0; i < 3; ++i)
            #pragma unroll
            for (int j = 0; j < 4; ++j)
                to[i * 4 + j] = (float)t[i][j];
        to[12] = 0.0f; to[13] = 0.0f; to[14] = 0.0f; to[15] = 1.0f;

        const double invden = 1.0 / (t[2][3] * t[2][3] + 1e-8);
        const double* st = (const double*)buf;
        float* oo = outg + (long long)NPROB * 16 + prob * 36;
        #pragma unroll
        for (int k = 0; k < 6; ++k)
            #pragma unroll
            for (int l = 0; l < 6; ++l)
                oo[k * 6 + l] = (float)(st[(long long)tid * 21 + ((k <= l) ? OI6(k, l) : OI6(l, k))] * invden);
    }
}

extern "C" void kernel_launch(void* const* d_in, const int* in_sizes, int n_in,
                              void* d_out, int out_size, void* d_ws, size_t ws_size,
                              hipStream_t stream) {
    const float* Mg = (const float*)d_in[0];  // [64,2048,13,13] fp32
    const float* Tg = (const float*)d_in[1];  // [64,2048,4,4]  fp32
    float* out = (float*)d_out;               // [NPROB*16 + NPROB*36] fp32
    (void)in_sizes; (void)n_in; (void)out_size; (void)d_ws; (void)ws_size;

    const int threads = 256;
    const int blocks = NPROB / threads;  // 512
    gn5_kernel<<<blocks, threads, 0, stream>>>(Mg, Tg, out);
}